// Round 5
// baseline (892.144 us; speedup 1.0000x reference)
//
#include <hip/hip_runtime.h>

#define CDIM 128
#define NC   8388608

// ws layout (float offsets):
//   nrm      @ 0       (960)
//   DT       @ 1024    (122880: DT0@+0, DT1@+8192, DT2@+24576, DT3@+57344)
//   keys     @ 131072  (262144 ints)
//   partials @ 393216  (32768 floats)

// ---- kernel 0: column norms + transposed dict copies ----
__global__ void vq_prep(const float* __restrict__ D0, const float* __restrict__ D1,
                        const float* __restrict__ D2, const float* __restrict__ D3,
                        float* __restrict__ nrm, float* __restrict__ DT) {
  int g = blockIdx.x * 256 + threadIdx.x;
  if (g >= 960) return;
  const float* D; int K, k; float* T;
  if (g < 64)       { D = D0; K = 64;  k = g;       T = DT; }
  else if (g < 192) { D = D1; K = 128; k = g - 64;  T = DT + 8192; }
  else if (g < 448) { D = D2; K = 256; k = g - 192; T = DT + 24576; }
  else              { D = D3; K = 512; k = g - 448; T = DT + 57344; }
  float s = 0.f;
  for (int c = 0; c < 128; ++c) {
    float v = D[c * K + k];
    s = fmaf(v, v, s);
    T[k * 128 + c] = v;
  }
  nrm[g] = s;
}

// one c-step: 1 row x 16 cols, all named regs
#define CSTEP1(CC, XC) { \
  const float* dr = Dp + (c4 * 4 + CC) * K; \
  float4 dv0 = *(const float4*)(dr); \
  float4 dv1 = *(const float4*)(dr + 4); \
  float4 dv2 = *(const float4*)(dr + 8); \
  float4 dv3 = *(const float4*)(dr + 12); \
  float xc = (XC); \
  a0.x = fmaf(xc, dv0.x, a0.x); a0.y = fmaf(xc, dv0.y, a0.y); \
  a0.z = fmaf(xc, dv0.z, a0.z); a0.w = fmaf(xc, dv0.w, a0.w); \
  a1.x = fmaf(xc, dv1.x, a1.x); a1.y = fmaf(xc, dv1.y, a1.y); \
  a1.z = fmaf(xc, dv1.z, a1.z); a1.w = fmaf(xc, dv1.w, a1.w); \
  a2.x = fmaf(xc, dv2.x, a2.x); a2.y = fmaf(xc, dv2.y, a2.y); \
  a2.z = fmaf(xc, dv2.z, a2.z); a2.w = fmaf(xc, dv2.w, a2.w); \
  a3.x = fmaf(xc, dv3.x, a3.x); a3.y = fmaf(xc, dv3.y, a3.y); \
  a3.z = fmaf(xc, dv3.z, a3.z); a3.w = fmaf(xc, dv3.w, a3.w); }

#define UPDA(AV, NV, OFF) cr = fmaf(-2.f, (AV), (NV)); \
  if (cr < best) { best = cr; bc = colbase + (OFF); }

template<int K>
__device__ __forceinline__ void scoreDict(
    const float* __restrict__ D, const float* __restrict__ nseg,
    const float4 (*__restrict__ xs)[33], const int l, const int wid, const int zv,
    float& best, int& bc)
{
  best = 1e30f; bc = 0;
  for (int tb = 0; tb < K; tb += 64) {
    const int colbase = __builtin_amdgcn_readfirstlane(tb + wid * 16);
    // zv is an opaque per-lane 0: forces VMEM (L1) broadcast loads, not SMEM
    const float* __restrict__ Dp = D + colbase + zv;
    float4 a0 = make_float4(0.f, 0.f, 0.f, 0.f);
    float4 a1 = a0, a2 = a0, a3 = a0;
    #pragma unroll 2
    for (int c4 = 0; c4 < 32; ++c4) {
      float4 xa = xs[l][c4];
      CSTEP1(0, xa.x)
      CSTEP1(1, xa.y)
      CSTEP1(2, xa.z)
      CSTEP1(3, xa.w)
    }
    const float* ns = nseg + colbase;
    float4 nv0 = *(const float4*)(ns);
    float4 nv1 = *(const float4*)(ns + 4);
    float4 nv2 = *(const float4*)(ns + 8);
    float4 nv3 = *(const float4*)(ns + 12);
    float cr;
    UPDA(a0.x, nv0.x, 0)  UPDA(a0.y, nv0.y, 1)  UPDA(a0.z, nv0.z, 2)  UPDA(a0.w, nv0.w, 3)
    UPDA(a1.x, nv1.x, 4)  UPDA(a1.y, nv1.y, 5)  UPDA(a1.z, nv1.z, 6)  UPDA(a1.w, nv1.w, 7)
    UPDA(a2.x, nv2.x, 8)  UPDA(a2.y, nv2.y, 9)  UPDA(a2.z, nv2.z, 10) UPDA(a2.w, nv2.w, 11)
    UPDA(a3.x, nv3.x, 12) UPDA(a3.y, nv3.y, 13) UPDA(a3.z, nv3.z, 14) UPDA(a3.w, nv3.w, 15)
  }
}

// ---- kernel 1: 64 rows/block, 4 blocks/CU resident, score all dicts ----
__global__ __launch_bounds__(256, 4) void vq_main(
    const float* __restrict__ x,
    const float* __restrict__ D0, const float* __restrict__ D1,
    const float* __restrict__ D2, const float* __restrict__ D3,
    const float* __restrict__ nrm, int* __restrict__ keys)
{
  __shared__ float4 xs[64][33];     // ~34 KB, stride 33 -> b128 reads near conflict-free
  __shared__ float2 cand[4][64];    // [wave][row] : (crit, col)

  const int t = threadIdx.x;
  const int l = t & 63;
  const int wid = t >> 6;

  int zv;
  asm volatile("v_mov_b32 %0, 0" : "=v"(zv));   // opaque lane-varying zero

  // stage 64-row x slab into LDS (coalesced)
  const float4* __restrict__ xg = (const float4*)x + (size_t)blockIdx.x * 2048;
  #pragma unroll
  for (int j = 0; j < 8; ++j) {
    int f = j * 256 + t;
    xs[f >> 5][f & 31] = xg[f];
  }
  __syncthreads();

  const int rowg = (blockIdx.x * 64 + t) << 2;   // key base for merge thread t (<64)
  float best; int bc;

  scoreDict< 64>(D0, nrm +   0, xs, l, wid, zv, best, bc);
  cand[wid][l] = make_float2(best, __int_as_float(bc));
  __syncthreads();
  if (t < 64) {
    float2 m = cand[0][t]; float mb = m.x; int mk = __float_as_int(m.y);
    #pragma unroll
    for (int w = 1; w < 4; ++w) {
      float2 c2 = cand[w][t]; int k2 = __float_as_int(c2.y);
      if (c2.x < mb || (c2.x == mb && k2 < mk)) { mb = c2.x; mk = k2; }
    }
    keys[rowg | 0] = mk;
  }
  __syncthreads();

  scoreDict<128>(D1, nrm +  64, xs, l, wid, zv, best, bc);
  cand[wid][l] = make_float2(best, __int_as_float(bc));
  __syncthreads();
  if (t < 64) {
    float2 m = cand[0][t]; float mb = m.x; int mk = __float_as_int(m.y);
    #pragma unroll
    for (int w = 1; w < 4; ++w) {
      float2 c2 = cand[w][t]; int k2 = __float_as_int(c2.y);
      if (c2.x < mb || (c2.x == mb && k2 < mk)) { mb = c2.x; mk = k2; }
    }
    keys[rowg | 1] = mk;
  }
  __syncthreads();

  scoreDict<256>(D2, nrm + 192, xs, l, wid, zv, best, bc);
  cand[wid][l] = make_float2(best, __int_as_float(bc));
  __syncthreads();
  if (t < 64) {
    float2 m = cand[0][t]; float mb = m.x; int mk = __float_as_int(m.y);
    #pragma unroll
    for (int w = 1; w < 4; ++w) {
      float2 c2 = cand[w][t]; int k2 = __float_as_int(c2.y);
      if (c2.x < mb || (c2.x == mb && k2 < mk)) { mb = c2.x; mk = k2; }
    }
    keys[rowg | 2] = mk;
  }
  __syncthreads();

  scoreDict<512>(D3, nrm + 448, xs, l, wid, zv, best, bc);
  cand[wid][l] = make_float2(best, __int_as_float(bc));
  __syncthreads();
  if (t < 64) {
    float2 m = cand[0][t]; float mb = m.x; int mk = __float_as_int(m.y);
    #pragma unroll
    for (int w = 1; w < 4; ++w) {
      float2 c2 = cand[w][t]; int k2 = __float_as_int(c2.y);
      if (c2.x < mb || (c2.x == mb && k2 < mk)) { mb = c2.x; mk = k2; }
    }
    keys[rowg | 3] = mk;
  }
}

// ---- kernel 2: gather winners (coalesced via DT), write out + loss partials ----
__global__ __launch_bounds__(256, 8) void vq_merge(
    const float* __restrict__ x, const float* __restrict__ DT,
    const int* __restrict__ keys,
    const float* __restrict__ alpha_p, const float* __restrict__ gamma_p,
    float* __restrict__ out, float* __restrict__ partials)
{
  __shared__ int kk[2][4];
  __shared__ float wr[4];
  const int t = threadIdx.x;
  const int c = t & 127, rs = t >> 7;
  const int row0 = blockIdx.x * 2;
  if (t < 8) {
    int r = t >> 2, d = t & 3;
    kk[r][d] = keys[((row0 + r) << 2) | d];
  }
  __syncthreads();
  const int row = row0 + rs;
  const float a = alpha_p[0];
  const float g0 = gamma_p[0], g1 = gamma_p[1], g2 = gamma_p[2], g3 = gamma_p[3];
  const float xv = x[(size_t)row * CDIM + c];
  const float d0 = DT[         kk[rs][0] * 128 + c];
  const float d1 = DT[ 8192  + kk[rs][1] * 128 + c];
  const float d2 = DT[ 24576 + kk[rs][2] * 128 + c];
  const float d3 = DT[ 57344 + kk[rs][3] * 128 + c];
  out[(size_t)row * CDIM + c] = a * (g0*d0 + g1*d1 + g2*d2 + g3*d3);
  float e0 = fmaf(-a, d0, xv), e1 = fmaf(-a, d1, xv);
  float e2 = fmaf(-a, d2, xv), e3 = fmaf(-a, d3, xv);
  float lc = g0*e0*e0 + g1*e1*e1 + g2*e2*e2 + g3*e3*e3;
  #pragma unroll
  for (int off = 32; off > 0; off >>= 1) lc += __shfl_down(lc, off);
  if ((t & 63) == 0) wr[t >> 6] = lc;
  __syncthreads();
  if (t == 0) partials[blockIdx.x] = wr[0] + wr[1] + wr[2] + wr[3];
}

// ---- kernel 3: final deterministic loss reduction ----
__global__ void vq_loss(const float* __restrict__ partials, float* __restrict__ lossp) {
  __shared__ float wr[4];
  const int t = threadIdx.x;
  float v = 0.f;
  #pragma unroll 8
  for (int i = 0; i < 128; ++i) v += partials[i * 256 + t];
  #pragma unroll
  for (int off = 32; off > 0; off >>= 1) v += __shfl_down(v, off);
  if ((t & 63) == 0) wr[t >> 6] = v;
  __syncthreads();
  if (t == 0) lossp[0] = (wr[0] + wr[1] + wr[2] + wr[3]) * (1.25f / 8388608.f);
}

extern "C" void kernel_launch(void* const* d_in, const int* in_sizes, int n_in,
                              void* d_out, int out_size, void* d_ws, size_t ws_size,
                              hipStream_t stream) {
  const float* x  = (const float*)d_in[0];
  const float* D0 = (const float*)d_in[1];
  const float* D1 = (const float*)d_in[2];
  const float* D2 = (const float*)d_in[3];
  const float* D3 = (const float*)d_in[4];
  const float* alpha = (const float*)d_in[5];
  const float* gamma = (const float*)d_in[6];
  float* out = (float*)d_out;

  float* ws = (float*)d_ws;
  float* nrm = ws;                        // 960
  float* DT  = ws + 1024;                 // 122880
  int*  keys = (int*)(ws + 131072);       // 262144 ints
  float* partials = ws + 393216;          // 32768

  vq_prep<<<4, 256, 0, stream>>>(D0, D1, D2, D3, nrm, DT);
  vq_main<<<1024, 256, 0, stream>>>(x, D0, D1, D2, D3, nrm, keys);
  vq_merge<<<32768, 256, 0, stream>>>(x, DT, keys, alpha, gamma, out, partials);
  vq_loss<<<1, 256, 0, stream>>>(partials, out + NC);
}

// Round 7
// 267.857 us; speedup vs baseline: 3.3307x; 3.3307x over previous
//
#include <hip/hip_runtime.h>

#define CDIM 128
#define NC   8388608
#define XPAD 68   // dw pad: 16B-aligned rows, reads 2-way bank max
#define SPAD 68

// ws layout (float offsets):
//   nrm      @ 0       (960)
//   DT       @ 1024    (122880: DT0@+0, DT1@+8192, DT2@+24576, DT3@+57344)
//   keys     @ 131072  (262144 ints)
//   partials @ 393216  (32768 floats)

// ---- kernel 0: column norms + transposed dict copies ----
__global__ void vq_prep(const float* __restrict__ D0, const float* __restrict__ D1,
                        const float* __restrict__ D2, const float* __restrict__ D3,
                        float* __restrict__ nrm, float* __restrict__ DT) {
  int g = blockIdx.x * 256 + threadIdx.x;
  if (g >= 960) return;
  const float* D; int K, k; float* T;
  if (g < 64)       { D = D0; K = 64;  k = g;       T = DT; }
  else if (g < 192) { D = D1; K = 128; k = g - 64;  T = DT + 8192; }
  else if (g < 448) { D = D2; K = 256; k = g - 192; T = DT + 24576; }
  else              { D = D3; K = 512; k = g - 448; T = DT + 57344; }
  float s = 0.f;
  for (int c = 0; c < 128; ++c) {
    float v = D[c * K + k];
    s = fmaf(v, v, s);
    T[k * 128 + c] = v;
  }
  nrm[g] = s;
}

// per-row criterion update, 4 ascending cols; strict < keeps lowest col
#define UPDR(BI, CI, AV) { \
  cr = fmaf(-2.f, (AV).x, nv.x); if (cr < (BI)) { (BI) = cr; (CI) = cb;     } \
  cr = fmaf(-2.f, (AV).y, nv.y); if (cr < (BI)) { (BI) = cr; (CI) = cb + 1; } \
  cr = fmaf(-2.f, (AV).z, nv.z); if (cr < (BI)) { (BI) = cr; (CI) = cb + 2; } \
  cr = fmaf(-2.f, (AV).w, nv.w); if (cr < (BI)) { (BI) = cr; (CI) = cb + 3; } }

// lex-min merge with shuffle partner
#define SMERGE(BI, CI) { \
  float pb = __shfl_xor((BI), m); int pk = __shfl_xor((CI), m); \
  if (pb < (BI) || (pb == (BI) && pk < (CI))) { (BI) = pb; (CI) = pk; } }

template<int K, int DICT>
__device__ __forceinline__ void scoreDict(
    const float* __restrict__ D, const float* __restrict__ nseg,
    float (*__restrict__ xt)[XPAD], float (*__restrict__ sd)[SPAD],
    float2 (*__restrict__ cand)[64],
    const int t, const int w, const int r0, const int cg, const int wc,
    int* __restrict__ keys)
{
  float b0 = 1e30f, b1 = 1e30f, b2 = 1e30f, b3 = 1e30f;
  int   k0 = 0, k1 = 0, k2 = 0, k3 = 0;

  for (int tb = 0; tb < K; tb += 64) {
    __syncthreads();   // previous tile's compute / merge done before restage
    // stage dict tile [128 c][64 cols] -> sd  (coalesced global, 2-way LDS)
    #pragma unroll
    for (int j = 0; j < 8; ++j) {
      int f = j * 256 + t;            // f4 index: c = f>>4, colq = f&15
      int c = f >> 4, cq = (f & 15) * 4;
      *(float4*)&sd[c][cq] = *(const float4*)(D + c * K + tb + cq);
    }
    __syncthreads();

    float4 a0 = make_float4(0.f, 0.f, 0.f, 0.f);
    float4 a1 = a0, a2 = a0, a3 = a0;
    #pragma unroll 4
    for (int c = 0; c < 128; ++c) {
      float4 xv = *(const float4*)&xt[c][r0];   // 4 rows, broadcast x4
      float4 dv = *(const float4*)&sd[c][wc];   // 4 cols, broadcast x16
      a0.x = fmaf(xv.x, dv.x, a0.x); a0.y = fmaf(xv.x, dv.y, a0.y);
      a0.z = fmaf(xv.x, dv.z, a0.z); a0.w = fmaf(xv.x, dv.w, a0.w);
      a1.x = fmaf(xv.y, dv.x, a1.x); a1.y = fmaf(xv.y, dv.y, a1.y);
      a1.z = fmaf(xv.y, dv.z, a1.z); a1.w = fmaf(xv.y, dv.w, a1.w);
      a2.x = fmaf(xv.z, dv.x, a2.x); a2.y = fmaf(xv.z, dv.y, a2.y);
      a2.z = fmaf(xv.z, dv.z, a2.z); a2.w = fmaf(xv.z, dv.w, a2.w);
      a3.x = fmaf(xv.w, dv.x, a3.x); a3.y = fmaf(xv.w, dv.y, a3.y);
      a3.z = fmaf(xv.w, dv.z, a3.z); a3.w = fmaf(xv.w, dv.w, a3.w);
    }

    const int cb = tb + wc;
    const float4 nv = *(const float4*)(nseg + cb);
    float cr;
    UPDR(b0, k0, a0)
    UPDR(b1, k1, a1)
    UPDR(b2, k2, a2)
    UPDR(b3, k3, a3)
  }

  // merge the 4 col-groups (lanes differing in low 2 bits) per row, lex order
  #pragma unroll
  for (int m = 1; m < 4; m <<= 1) {
    SMERGE(b0, k0) SMERGE(b1, k1) SMERGE(b2, k2) SMERGE(b3, k3)
  }
  if (cg == 0) {
    cand[w][r0 + 0] = make_float2(b0, __int_as_float(k0));
    cand[w][r0 + 1] = make_float2(b1, __int_as_float(k1));
    cand[w][r0 + 2] = make_float2(b2, __int_as_float(k2));
    cand[w][r0 + 3] = make_float2(b3, __int_as_float(k3));
  }
  __syncthreads();
  if (t < 64) {
    float2 mm = cand[0][t]; float mb = mm.x; int mk = __float_as_int(mm.y);
    #pragma unroll
    for (int w2 = 1; w2 < 4; ++w2) {
      float2 c2 = cand[w2][t]; int kk = __float_as_int(c2.y);
      if (c2.x < mb || (c2.x == mb && kk < mk)) { mb = c2.x; mk = kk; }
    }
    keys[((blockIdx.x * 64 + t) << 2) | DICT] = mk;
  }
}

// ---- kernel 1: register-tiled LDS GEMM scoring; 64 rows/block ----
__global__ __launch_bounds__(256, 2) void vq_main(
    const float* __restrict__ x,
    const float* __restrict__ D0, const float* __restrict__ D1,
    const float* __restrict__ D2, const float* __restrict__ D3,
    const float* __restrict__ nrm, int* __restrict__ keys)
{
  __shared__ float  xt[128][XPAD];   // [c][row]  ~34.8 KB
  __shared__ float  sd[128][SPAD];   // [c][col]  ~34.8 KB
  __shared__ float2 cand[4][64];     // 2 KB

  const int t  = threadIdx.x;
  const int l  = t & 63;
  const int w  = t >> 6;
  const int r0 = (l >> 2) * 4;       // lane's 4 rows
  const int cg = l & 3;
  const int wc = w * 16 + cg * 4;    // lane's 4 cols within 64-col tile

  // stage x transposed: [row][c] global -> [c][row] LDS
  const float4* __restrict__ xg = (const float4*)x + (size_t)blockIdx.x * 2048;
  #pragma unroll
  for (int j = 0; j < 8; ++j) {
    int f = j * 256 + t;             // row = f>>5, c4 = f&31
    float4 v = xg[f];
    int row = f >> 5, c0 = (f & 31) * 4;
    xt[c0 + 0][row] = v.x;
    xt[c0 + 1][row] = v.y;
    xt[c0 + 2][row] = v.z;
    xt[c0 + 3][row] = v.w;
  }
  // scoreDict's leading __syncthreads() covers the staging barrier

  scoreDict< 64, 0>(D0, nrm +   0, xt, sd, cand, t, w, r0, cg, wc, keys);
  scoreDict<128, 1>(D1, nrm +  64, xt, sd, cand, t, w, r0, cg, wc, keys);
  scoreDict<256, 2>(D2, nrm + 192, xt, sd, cand, t, w, r0, cg, wc, keys);
  scoreDict<512, 3>(D3, nrm + 448, xt, sd, cand, t, w, r0, cg, wc, keys);
}

// ---- kernel 2: gather winners (coalesced via DT), write out + loss partials ----
__global__ __launch_bounds__(256, 8) void vq_merge(
    const float* __restrict__ x, const float* __restrict__ DT,
    const int* __restrict__ keys,
    const float* __restrict__ alpha_p, const float* __restrict__ gamma_p,
    float* __restrict__ out, float* __restrict__ partials)
{
  __shared__ int kk[2][4];
  __shared__ float wr[4];
  const int t = threadIdx.x;
  const int c = t & 127, rs = t >> 7;
  const int row0 = blockIdx.x * 2;
  if (t < 8) {
    int r = t >> 2, d = t & 3;
    kk[r][d] = keys[((row0 + r) << 2) | d];
  }
  __syncthreads();
  const int row = row0 + rs;
  const float a = alpha_p[0];
  const float g0 = gamma_p[0], g1 = gamma_p[1], g2 = gamma_p[2], g3 = gamma_p[3];
  const float xv = x[(size_t)row * CDIM + c];
  const float d0 = DT[         kk[rs][0] * 128 + c];
  const float d1 = DT[ 8192  + kk[rs][1] * 128 + c];
  const float d2 = DT[ 24576 + kk[rs][2] * 128 + c];
  const float d3 = DT[ 57344 + kk[rs][3] * 128 + c];
  out[(size_t)row * CDIM + c] = a * (g0*d0 + g1*d1 + g2*d2 + g3*d3);
  float e0 = fmaf(-a, d0, xv), e1 = fmaf(-a, d1, xv);
  float e2 = fmaf(-a, d2, xv), e3 = fmaf(-a, d3, xv);
  float lc = g0*e0*e0 + g1*e1*e1 + g2*e2*e2 + g3*e3*e3;
  #pragma unroll
  for (int off = 32; off > 0; off >>= 1) lc += __shfl_down(lc, off);
  if ((t & 63) == 0) wr[t >> 6] = lc;
  __syncthreads();
  if (t == 0) partials[blockIdx.x] = wr[0] + wr[1] + wr[2] + wr[3];
}

// ---- kernel 3: final deterministic loss reduction ----
__global__ void vq_loss(const float* __restrict__ partials, float* __restrict__ lossp) {
  __shared__ float wr[4];
  const int t = threadIdx.x;
  float v = 0.f;
  #pragma unroll 8
  for (int i = 0; i < 128; ++i) v += partials[i * 256 + t];
  #pragma unroll
  for (int off = 32; off > 0; off >>= 1) v += __shfl_down(v, off);
  if ((t & 63) == 0) wr[t >> 6] = v;
  __syncthreads();
  if (t == 0) lossp[0] = (wr[0] + wr[1] + wr[2] + wr[3]) * (1.25f / 8388608.f);
}

extern "C" void kernel_launch(void* const* d_in, const int* in_sizes, int n_in,
                              void* d_out, int out_size, void* d_ws, size_t ws_size,
                              hipStream_t stream) {
  const float* x  = (const float*)d_in[0];
  const float* D0 = (const float*)d_in[1];
  const float* D1 = (const float*)d_in[2];
  const float* D2 = (const float*)d_in[3];
  const float* D3 = (const float*)d_in[4];
  const float* alpha = (const float*)d_in[5];
  const float* gamma = (const float*)d_in[6];
  float* out = (float*)d_out;

  float* ws = (float*)d_ws;
  float* nrm = ws;                        // 960
  float* DT  = ws + 1024;                 // 122880
  int*  keys = (int*)(ws + 131072);       // 262144 ints
  float* partials = ws + 393216;          // 32768

  vq_prep<<<4, 256, 0, stream>>>(D0, D1, D2, D3, nrm, DT);
  vq_main<<<1024, 256, 0, stream>>>(x, D0, D1, D2, D3, nrm, keys);
  vq_merge<<<32768, 256, 0, stream>>>(x, DT, keys, alpha, gamma, out, partials);
  vq_loss<<<1, 256, 0, stream>>>(partials, out + NC);
}